// Round 1
// baseline (875.912 us; speedup 1.0000x reference)
//
#include <hip/hip_runtime.h>
#include <cstdint>
#include <cstddef>

#define T_STEPS 20
#define B_SZ 128
#define H_SZ 256
#define E_SZ 128
#define C_SZ 512
#define V_SZ 32000
#define G4H 1024

typedef __bf16 bf16x8 __attribute__((ext_vector_type(8)));
typedef float f32x4 __attribute__((ext_vector_type(4)));
typedef unsigned short u16x8 __attribute__((ext_vector_type(8)));

__device__ __forceinline__ unsigned short f2bf(float f) {
  unsigned int u = __builtin_bit_cast(unsigned int, f);
  u += 0x7fffu + ((u >> 16) & 1u);   // round-to-nearest-even
  return (unsigned short)(u >> 16);
}

// ---------- K0a: Wp f32 -> bf16 ----------
__global__ __launch_bounds__(256) void k_wp_conv(const float* __restrict__ src,
                                                 unsigned short* __restrict__ dst, int n4) {
  int i = blockIdx.x * 256 + threadIdx.x;
  if (i >= n4) return;
  const float4 v = ((const float4*)src)[i];
  ushort4 o;
  o.x = f2bf(v.x); o.y = f2bf(v.y); o.z = f2bf(v.z); o.w = f2bf(v.w);
  ((ushort4*)dst)[i] = o;
}

// ---------- K0b: broadcast h0 ----------
__global__ __launch_bounds__(256) void k_h0_init(const float* __restrict__ h1,
                                                 const float* __restrict__ h2,
                                                 float* __restrict__ h0) {
  int idx = blockIdx.x * 256 + threadIdx.x;  // 0..65535 = [2][128][256]
  int l = idx >> 15;
  int j = idx & 255;
  h0[idx] = l ? h2[j] : h1[j];
}

// ---------- K1a: ctxg[l,b,g] = context[b,:] @ Wih_l[g,128:640] + bih_l[g] + bhh_l[g] ----------
__global__ __launch_bounds__(256) void k_ctx_gemm(const float* __restrict__ context,
    const float* __restrict__ Wih_p, const float* __restrict__ Wih_n,
    const float* __restrict__ bih_p, const float* __restrict__ bhh_p,
    const float* __restrict__ bih_n, const float* __restrict__ bhh_n,
    float* __restrict__ ctxg) {
  const int bid = blockIdx.x;          // 128 blocks: l(2) x btile(16) x gtile(4)
  const int l = bid >> 6;
  const int bt = (bid >> 2) & 15;
  const int gt = bid & 3;
  const int b0 = bt * 8;
  const int g = gt * 256 + threadIdx.x;
  __shared__ float csh[8][C_SZ];
  for (int i = threadIdx.x; i < 8 * C_SZ; i += 256)
    csh[i >> 9][i & 511] = context[(size_t)(b0 + (i >> 9)) * C_SZ + (i & 511)];
  __syncthreads();
  const float* W = (l ? Wih_n : Wih_p) + (size_t)g * 640 + E_SZ;
  float acc[8] = {};
  for (int c = 0; c < C_SZ; c += 4) {
    const float4 w = *(const float4*)(W + c);
#pragma unroll
    for (int bb = 0; bb < 8; ++bb) {
      const float4 h = *(const float4*)(&csh[bb][c]);
      acc[bb] += w.x * h.x + w.y * h.y + w.z * h.z + w.w * h.w;
    }
  }
  const float bias = l ? (bih_n[g] + bhh_n[g]) : (bih_p[g] + bhh_p[g]);
#pragma unroll
  for (int bb = 0; bb < 8; ++bb)
    ctxg[((size_t)l * B_SZ + b0 + bb) * G4H + g] = acc[bb] + bias;
}

// ---------- K1b: xg[l,r,g] = input_l[r,:] @ Wih_l[g,0:128] + ctxg[l, r&127, g] ----------
__global__ __launch_bounds__(256) void k_in_gemm(const float* __restrict__ inP,
    const float* __restrict__ inN,
    const float* __restrict__ Wih_p, const float* __restrict__ Wih_n,
    const float* __restrict__ ctxg, float* __restrict__ xg) {
  const int bid = blockIdx.x;          // 1280 blocks: l(2) x rowtile(160) x gtile(4)
  const int l = bid / 640;
  const int rest = bid % 640;
  const int rt = rest >> 2;
  const int gt = rest & 3;
  const int r0 = rt * 16;
  const int g = gt * 256 + threadIdx.x;
  __shared__ float ish[16][E_SZ];
  const float* inp = l ? inN : inP;
  for (int i = threadIdx.x; i < 16 * E_SZ; i += 256)
    ish[i >> 7][i & 127] = inp[(size_t)(r0 + (i >> 7)) * E_SZ + (i & 127)];
  __syncthreads();
  const float* W = (l ? Wih_n : Wih_p) + (size_t)g * 640;
  float acc[16] = {};
  for (int k = 0; k < E_SZ; k += 4) {
    const float4 w = *(const float4*)(W + k);
#pragma unroll
    for (int rr = 0; rr < 16; ++rr) {
      const float4 h = *(const float4*)(&ish[rr][k]);
      acc[rr] += w.x * h.x + w.y * h.y + w.z * h.z + w.w * h.w;
    }
  }
#pragma unroll
  for (int rr = 0; rr < 16; ++rr) {
    const int b = (r0 + rr) & 127;
    const float cv = ctxg[((size_t)l * B_SZ + b) * G4H + g];
    xg[((size_t)l * (T_STEPS * B_SZ) + r0 + rr) * G4H + g] = acc[rr] + cv;
  }
}

// ---------- K2: one LSTM time step for both lstms (f-gate dead: c0 == 0) ----------
__global__ __launch_bounds__(256) void k_lstm_step(const float* __restrict__ xg,
    const float* __restrict__ Whh_p, const float* __restrict__ Whh_n,
    const float* __restrict__ h0, float* __restrict__ hs,
    unsigned short* __restrict__ hsb, int t) {
  const int bid = blockIdx.x;          // 64 blocks: l(2) x btile(32), 4 b each
  const int l = bid >> 5;
  const int b0 = (bid & 31) * 4;
  const int j = threadIdx.x;           // output column 0..255
  __shared__ float hsh[4][H_SZ];
  const float* hp = (t == 0) ? (h0 + (size_t)l * B_SZ * H_SZ)
                             : (hs + ((size_t)l * T_STEPS + (t - 1)) * B_SZ * H_SZ);
  for (int i = threadIdx.x; i < 4 * H_SZ; i += 256)
    hsh[i >> 8][i & 255] = hp[(size_t)(b0 + (i >> 8)) * H_SZ + (i & 255)];
  __syncthreads();
  const float* Whh = l ? Whh_n : Whh_p;
  const float* wi = Whh + (size_t)j * H_SZ;
  const float* wg = Whh + (size_t)(2 * H_SZ + j) * H_SZ;
  const float* wo = Whh + (size_t)(3 * H_SZ + j) * H_SZ;
  float ai[4] = {}, ag[4] = {}, ao[4] = {};
  for (int k = 0; k < H_SZ; k += 4) {
    const float4 vi = *(const float4*)(wi + k);
    const float4 vg = *(const float4*)(wg + k);
    const float4 vo = *(const float4*)(wo + k);
#pragma unroll
    for (int bb = 0; bb < 4; ++bb) {
      const float4 h = *(const float4*)(&hsh[bb][k]);
      ai[bb] += vi.x * h.x + vi.y * h.y + vi.z * h.z + vi.w * h.w;
      ag[bb] += vg.x * h.x + vg.y * h.y + vg.z * h.z + vg.w * h.w;
      ao[bb] += vo.x * h.x + vo.y * h.y + vo.z * h.z + vo.w * h.w;
    }
  }
  const size_t xslab = ((size_t)l * T_STEPS + t) * B_SZ;
#pragma unroll
  for (int bb = 0; bb < 4; ++bb) {
    const size_t xrow = (xslab + b0 + bb) * G4H;
    const float gi = xg[xrow + j] + ai[bb];
    const float gg = xg[xrow + 2 * H_SZ + j] + ag[bb];
    const float go = xg[xrow + 3 * H_SZ + j] + ao[bb];
    const float c = (1.0f / (1.0f + expf(-gi))) * tanhf(gg);
    const float h = (1.0f / (1.0f + expf(-go))) * tanhf(c);
    const size_t o = xslab * H_SZ + (size_t)(b0 + bb) * H_SZ + j;
    hs[o] = h;
    hsb[o] = f2bf(h);
  }
}

// ---------- K3: projection GEMM  out[5120,32000] = hs_bf16[5120,256] @ Wp_bf16[32000,256]^T + bp ----------
__global__ __launch_bounds__(256) void k_proj(const unsigned short* __restrict__ A,
    const unsigned short* __restrict__ Bw, const float* __restrict__ bias,
    float* __restrict__ out) {
  __shared__ unsigned short As[128 * 64];
  __shared__ unsigned short Bs[128 * 64];
  const int tid = threadIdx.x;
  const int wave = tid >> 6;
  const int lane = tid & 63;
  // XCD-chunk swizzle (10000 = 8 * 1250, bijective), then N-major so same-N blocks
  // share the Wp panel in one XCD's L2; A (2.6MB bf16) is L2-resident anyway.
  const int bid = blockIdx.x;
  const int nb = (bid & 7) * 1250 + (bid >> 3);
  const int mt = nb % 40;
  const int nt = nb / 40;
  const int m0 = mt * 128;
  const int n0 = nt * 128;
  const int wr = wave >> 1, wc = wave & 1;
  f32x4 acc[4][4] = {};
  for (int k0 = 0; k0 < 256; k0 += 64) {
#pragma unroll
    for (int j = 0; j < 4; ++j) {
      const int c = (j * 4 + wave) * 64 + lane;   // 16B-chunk index 0..1023
      const int row = c >> 3, col8 = c & 7;
      const unsigned short* srcA = A + (size_t)(m0 + row) * 256 + k0 + col8 * 8;
      const unsigned short* srcB = Bw + (size_t)(n0 + row) * 256 + k0 + col8 * 8;
      __builtin_amdgcn_global_load_lds((const __attribute__((address_space(1))) void*)srcA,
          (__attribute__((address_space(3))) void*)(As + c * 8), 16, 0, 0);
      __builtin_amdgcn_global_load_lds((const __attribute__((address_space(1))) void*)srcB,
          (__attribute__((address_space(3))) void*)(Bs + c * 8), 16, 0, 0);
    }
    asm volatile("s_waitcnt vmcnt(0)" ::: "memory");
    __syncthreads();
#pragma unroll
    for (int kk = 0; kk < 64; kk += 32) {
      const int kb = kk + (lane >> 4) * 8;
      bf16x8 af[4], bfr[4];
#pragma unroll
      for (int mi = 0; mi < 4; ++mi) {
        const int r = wr * 64 + mi * 16 + (lane & 15);
        af[mi] = __builtin_bit_cast(bf16x8, *(const u16x8*)(As + r * 64 + kb));
      }
#pragma unroll
      for (int ni = 0; ni < 4; ++ni) {
        const int r = wc * 64 + ni * 16 + (lane & 15);
        bfr[ni] = __builtin_bit_cast(bf16x8, *(const u16x8*)(Bs + r * 64 + kb));
      }
#pragma unroll
      for (int mi = 0; mi < 4; ++mi)
#pragma unroll
        for (int ni = 0; ni < 4; ++ni)
          acc[mi][ni] = __builtin_amdgcn_mfma_f32_16x16x32_bf16(af[mi], bfr[ni], acc[mi][ni], 0, 0, 0);
    }
    __syncthreads();
  }
#pragma unroll
  for (int ni = 0; ni < 4; ++ni) {
    const int col = n0 + wc * 64 + ni * 16 + (lane & 15);
    const float bv = bias[col];
#pragma unroll
    for (int mi = 0; mi < 4; ++mi) {
#pragma unroll
      for (int i = 0; i < 4; ++i) {
        const int row = m0 + wr * 64 + mi * 16 + (lane >> 4) * 4 + i;
        out[(size_t)row * V_SZ + col] = acc[mi][ni][i] + bv;
      }
    }
  }
}

extern "C" void kernel_launch(void* const* d_in, const int* in_sizes, int n_in,
                              void* d_out, int out_size, void* d_ws, size_t ws_size,
                              hipStream_t stream) {
  (void)in_sizes; (void)n_in; (void)out_size; (void)ws_size;
  const float* inputPrev = (const float*)d_in[0];
  const float* inputNext = (const float*)d_in[1];
  const float* context   = (const float*)d_in[2];
  const float* hidden1   = (const float*)d_in[3];
  const float* hidden2   = (const float*)d_in[4];
  const float* Wih_p = (const float*)d_in[5];
  const float* Whh_p = (const float*)d_in[6];
  const float* bih_p = (const float*)d_in[7];
  const float* bhh_p = (const float*)d_in[8];
  const float* Wih_n = (const float*)d_in[9];
  const float* Whh_n = (const float*)d_in[10];
  const float* bih_n = (const float*)d_in[11];
  const float* bhh_n = (const float*)d_in[12];
  const float* Wp = (const float*)d_in[13];
  const float* bp = (const float*)d_in[14];
  float* out = (float*)d_out;

  // workspace carve (all offsets 4KB-aligned); total 46,530,560 B
  char* ws = (char*)d_ws;
  float* xg_all        = (float*)(ws + 0);          // [2][20][128][1024] f32 = 20,971,520
  float* ctxg          = (float*)(ws + 20971520);   // [2][128][1024] f32   =  1,048,576
  float* h0            = (float*)(ws + 22020096);   // [2][128][256] f32    =    262,144
  float* hs            = (float*)(ws + 22282240);   // [2][20][128][256] f32=  5,242,880
  unsigned short* hsb  = (unsigned short*)(ws + 27525120); // bf16 copy     =  2,621,440
  unsigned short* Wpb  = (unsigned short*)(ws + 30146560); // [32000][256]  = 16,384,000

  k_wp_conv<<<8000, 256, 0, stream>>>(Wp, Wpb, 2048000);
  k_h0_init<<<256, 256, 0, stream>>>(hidden1, hidden2, h0);
  k_ctx_gemm<<<128, 256, 0, stream>>>(context, Wih_p, Wih_n, bih_p, bhh_p, bih_n, bhh_n, ctxg);
  k_in_gemm<<<1280, 256, 0, stream>>>(inputPrev, inputNext, Wih_p, Wih_n, ctxg, xg_all);
  for (int t = 0; t < T_STEPS; ++t)
    k_lstm_step<<<64, 256, 0, stream>>>(xg_all, Whh_p, Whh_n, h0, hs, hsb, t);
  k_proj<<<10000, 256, 0, stream>>>(hsb, Wpb, bp, out);
}

// Round 2
// 487.142 us; speedup vs baseline: 1.7981x; 1.7981x over previous
//
#include <hip/hip_runtime.h>
#include <cstdint>
#include <cstddef>

#define T_STEPS 20
#define B_SZ 128
#define H_SZ 256
#define E_SZ 128
#define C_SZ 512
#define V_SZ 32000
#define G4H 1024

typedef __bf16 bf16x8 __attribute__((ext_vector_type(8)));
typedef float f32x4 __attribute__((ext_vector_type(4)));
typedef unsigned short u16x8 __attribute__((ext_vector_type(8)));

#define AS1 __attribute__((address_space(1)))
#define AS3 __attribute__((address_space(3)))

__device__ __forceinline__ unsigned short f2bf(float f) {
  unsigned int u = __builtin_bit_cast(unsigned int, f);
  u += 0x7fffu + ((u >> 16) & 1u);   // round-to-nearest-even
  return (unsigned short)(u >> 16);
}

// ---------- K0: prep — Whh (i,g,o rows) -> bf16 pre-swizzled panels; h0 -> hsb slot 0 ----------
// whh_bs layout: [l][tile(8)][n(96)][k(256)] bf16, element (n,k) holds Whh[row(n)][k ^ ((n&7)<<3)]
// hsb layout:    [l][slot(21)][b(128)][k(256)] bf16, element (b,k) holds h[b][k ^ ((b&7)<<3)]
__global__ __launch_bounds__(256) void k_prep(const float* __restrict__ Whh_p,
    const float* __restrict__ Whh_n, const float* __restrict__ h1, const float* __restrict__ h2,
    unsigned short* __restrict__ whh_bs, unsigned short* __restrict__ hsb) {
  const int idx = blockIdx.x * 256 + threadIdx.x;
  const int NW = 2 * 8 * 96 * 256;
  if (idx < NW) {
    const int k = idx & 255;
    const int n = (idx >> 8) % 96;
    const int tile = ((idx >> 8) / 96) & 7;
    const int l = idx / (8 * 96 * 256);
    const int gate = n >> 5;
    const int c = n & 31;
    const int row = (gate == 0 ? 0 : (gate == 1 ? 512 : 768)) + tile * 32 + c;
    const int ksrc = (k & 7) | (((k >> 3) ^ (n & 7)) << 3);
    const float* W = l ? Whh_n : Whh_p;
    whh_bs[idx] = f2bf(W[(size_t)row * 256 + ksrc]);
  } else {
    const int i2 = idx - NW;          // [2][128][256]
    const int k = i2 & 255;
    const int b = (i2 >> 8) & 127;
    const int l = i2 >> 15;
    const int ksrc = (k & 7) | (((k >> 3) ^ (b & 7)) << 3);
    const float* h = l ? h2 : h1;     // [1,256] broadcast row
    hsb[(size_t)(l * 21) * 32768 + (size_t)b * 256 + k] = f2bf(h[ksrc]);
  }
}

// ---------- K1a: ctxg[l,b,g] = context[b,:] @ Wih_l[g,128:640] + bih_l[g] + bhh_l[g] ----------
__global__ __launch_bounds__(256) void k_ctx_gemm(const float* __restrict__ context,
    const float* __restrict__ Wih_p, const float* __restrict__ Wih_n,
    const float* __restrict__ bih_p, const float* __restrict__ bhh_p,
    const float* __restrict__ bih_n, const float* __restrict__ bhh_n,
    float* __restrict__ ctxg) {
  const int bid = blockIdx.x;          // 128 blocks: l(2) x btile(16) x gtile(4)
  const int l = bid >> 6;
  const int bt = (bid >> 2) & 15;
  const int gt = bid & 3;
  const int b0 = bt * 8;
  const int g = gt * 256 + threadIdx.x;
  __shared__ float csh[8][C_SZ];
  for (int i = threadIdx.x; i < 8 * C_SZ; i += 256)
    csh[i >> 9][i & 511] = context[(size_t)(b0 + (i >> 9)) * C_SZ + (i & 511)];
  __syncthreads();
  const float* W = (l ? Wih_n : Wih_p) + (size_t)g * 640 + E_SZ;
  float acc[8] = {};
  for (int c = 0; c < C_SZ; c += 4) {
    const float4 w = *(const float4*)(W + c);
#pragma unroll
    for (int bb = 0; bb < 8; ++bb) {
      const float4 h = *(const float4*)(&csh[bb][c]);
      acc[bb] += w.x * h.x + w.y * h.y + w.z * h.z + w.w * h.w;
    }
  }
  const float bias = l ? (bih_n[g] + bhh_n[g]) : (bih_p[g] + bhh_p[g]);
#pragma unroll
  for (int bb = 0; bb < 8; ++bb)
    ctxg[((size_t)l * B_SZ + b0 + bb) * G4H + g] = acc[bb] + bias;
}

// ---------- K1b: xg[l,r,g] = input_l[r,:] @ Wih_l[g,0:128] + ctxg[l, r&127, g] ----------
__global__ __launch_bounds__(256) void k_in_gemm(const float* __restrict__ inP,
    const float* __restrict__ inN,
    const float* __restrict__ Wih_p, const float* __restrict__ Wih_n,
    const float* __restrict__ ctxg, float* __restrict__ xg) {
  const int bid = blockIdx.x;          // 1280 blocks: l(2) x rowtile(160) x gtile(4)
  const int l = bid / 640;
  const int rest = bid % 640;
  const int rt = rest >> 2;
  const int gt = rest & 3;
  const int r0 = rt * 16;
  const int g = gt * 256 + threadIdx.x;
  __shared__ float ish[16][E_SZ];
  const float* inp = l ? inN : inP;
  for (int i = threadIdx.x; i < 16 * E_SZ; i += 256)
    ish[i >> 7][i & 127] = inp[(size_t)(r0 + (i >> 7)) * E_SZ + (i & 127)];
  __syncthreads();
  const float* W = (l ? Wih_n : Wih_p) + (size_t)g * 640;
  float acc[16] = {};
  for (int k = 0; k < E_SZ; k += 4) {
    const float4 w = *(const float4*)(W + k);
#pragma unroll
    for (int rr = 0; rr < 16; ++rr) {
      const float4 h = *(const float4*)(&ish[rr][k]);
      acc[rr] += w.x * h.x + w.y * h.y + w.z * h.z + w.w * h.w;
    }
  }
#pragma unroll
  for (int rr = 0; rr < 16; ++rr) {
    const int b = (r0 + rr) & 127;
    const float cv = ctxg[((size_t)l * B_SZ + b) * G4H + g];
    xg[((size_t)l * (T_STEPS * B_SZ) + r0 + rr) * G4H + g] = acc[rr] + cv;
  }
}

// ---------- K2: one LSTM time step (MFMA, f-gate dead since c0 == 0) ----------
// grid 16 = l(2) x tile(8); block 256. Per block: N = 96 gate-rows (3 gates x 32 h-cols),
// M = 128 batches, K = 256. h and Whh panel staged in LDS (both pre-swizzled globally).
__global__ __launch_bounds__(256, 1) void k_step(const unsigned short* __restrict__ hsb,
    const unsigned short* __restrict__ whh_bs, const float* __restrict__ xg,
    unsigned short* __restrict__ hsb_out, int t) {
  __shared__ unsigned short hls[128 * 256];   // 64 KB
  __shared__ unsigned short wls[96 * 256];    // 48 KB
  const int tid = threadIdx.x;
  const int lane = tid & 63;
  const int wave = tid >> 6;
  const int l = blockIdx.x >> 3;
  const int tile = blockIdx.x & 7;
  const unsigned short* hsrc = hsb + (size_t)(l * 21 + t) * 32768 + tid * 8;
  const unsigned short* wsrc = whh_bs + (size_t)(l * 8 + tile) * 24576 + tid * 8;
#pragma unroll
  for (int i = 0; i < 16; ++i)
    __builtin_amdgcn_global_load_lds((const AS1 void*)(hsrc + i * 2048),
                                     (AS3 void*)(hls + tid * 8 + i * 2048), 16, 0, 0);
#pragma unroll
  for (int i = 0; i < 12; ++i)
    __builtin_amdgcn_global_load_lds((const AS1 void*)(wsrc + i * 2048),
                                     (AS3 void*)(wls + tid * 8 + i * 2048), 16, 0, 0);
  asm volatile("s_waitcnt vmcnt(0)" ::: "memory");
  __builtin_amdgcn_s_barrier();
  f32x4 acc[2][6] = {};
#pragma unroll
  for (int kf = 0; kf < 8; ++kf) {
    const int ch = kf * 4 + (lane >> 4);
    bf16x8 bf[6];
#pragma unroll
    for (int nt = 0; nt < 6; ++nt) {
      const int n = nt * 16 + (lane & 15);
      bf[nt] = __builtin_bit_cast(bf16x8, *(const u16x8*)(wls + n * 256 + ((ch ^ (n & 7)) << 3)));
    }
#pragma unroll
    for (int m = 0; m < 2; ++m) {
      const int b = wave * 32 + m * 16 + (lane & 15);
      const bf16x8 af = __builtin_bit_cast(bf16x8, *(const u16x8*)(hls + b * 256 + ((ch ^ (b & 7)) << 3)));
#pragma unroll
      for (int nt = 0; nt < 6; ++nt)
        acc[m][nt] = __builtin_amdgcn_mfma_f32_16x16x32_bf16(af, bf[nt], acc[m][nt], 0, 0, 0);
    }
  }
  const size_t xbase = ((size_t)(l * T_STEPS + t) * B_SZ) * G4H;
  unsigned short* hout = hsb_out + (size_t)(l * 21 + 1 + t) * 32768;
#pragma unroll
  for (int m = 0; m < 2; ++m) {
#pragma unroll
    for (int cp = 0; cp < 2; ++cp) {
      const int j = tile * 32 + cp * 16 + (lane & 15);
#pragma unroll
      for (int i = 0; i < 4; ++i) {
        const int b = wave * 32 + m * 16 + (lane >> 4) * 4 + i;
        const size_t xr = xbase + (size_t)b * G4H;
        const float gi = xg[xr + j]       + acc[m][cp][i];
        const float gg = xg[xr + 512 + j] + acc[m][2 + cp][i];
        const float go = xg[xr + 768 + j] + acc[m][4 + cp][i];
        const float c = (1.0f / (1.0f + expf(-gi))) * tanhf(gg);
        const float h = (1.0f / (1.0f + expf(-go))) * tanhf(c);
        const int kpos = (j & 7) | (((j >> 3) ^ (b & 7)) << 3);
        hout[(size_t)b * 256 + kpos] = f2bf(h);
      }
    }
  }
}

// ---------- K3: projection  out[5120,32000] = hs_bf16[5120,256] @ Wp[32000,256]^T + bp ----------
// 500 blocks x 64-col strip. Wp panel converted f32->bf16 into register B-frags once.
// A tiles (32 rows) triple-buffered via global_load_lds, counted vmcnt, raw barriers.
__global__ __launch_bounds__(256, 2) void k_proj(const unsigned short* __restrict__ hsb,
    const float* __restrict__ Wp, const float* __restrict__ bias, float* __restrict__ out) {
  __shared__ unsigned short smem[3 * 32 * 256];   // 3 x 16 KB A buffers
  const int tid = threadIdx.x;
  const int lane = tid & 63;
  const int wave = tid >> 6;
  const int wgrp = wave >> 1;       // row half of 32-row tile
  const int wc = wave & 1;          // col half of 64-col strip
  const int n_base = blockIdx.x * 64 + wc * 32;
  // B panel -> registers (bf16 frags)
  bf16x8 bfr[2][8];
#pragma unroll
  for (int nt = 0; nt < 2; ++nt) {
    const int n_g = n_base + nt * 16 + (lane & 15);
    const float* src = Wp + (size_t)n_g * 256 + (lane >> 4) * 8;
#pragma unroll
    for (int kf = 0; kf < 8; ++kf) {
      const float4 a = *(const float4*)(src + kf * 32);
      const float4 b = *(const float4*)(src + kf * 32 + 4);
      u16x8 u;
      u[0] = f2bf(a.x); u[1] = f2bf(a.y); u[2] = f2bf(a.z); u[3] = f2bf(a.w);
      u[4] = f2bf(b.x); u[5] = f2bf(b.y); u[6] = f2bf(b.z); u[7] = f2bf(b.w);
      bfr[nt][kf] = __builtin_bit_cast(bf16x8, u);
    }
  }
  const float bv0 = bias[n_base + (lane & 15)];
  const float bv1 = bias[n_base + 16 + (lane & 15)];

#define STAGE_A(IT, BUF)                                                                   \
  {                                                                                        \
    const int it_ = (IT);                                                                  \
    const int l_ = it_ >= 80;                                                              \
    const int t_ = (it_ - l_ * 80) >> 2;                                                   \
    const int b0_ = (it_ & 3) * 32;                                                        \
    const unsigned short* src_ = hsb + (size_t)(l_ * 21 + 1 + t_) * 32768 + b0_ * 256 + tid * 8; \
    unsigned short* dst_ = smem + (BUF) * 8192 + tid * 8;                                  \
    _Pragma("unroll")                                                                      \
    for (int i_ = 0; i_ < 4; ++i_)                                                         \
      __builtin_amdgcn_global_load_lds((const AS1 void*)(src_ + i_ * 2048),                \
                                       (AS3 void*)(dst_ + i_ * 2048), 16, 0, 0);           \
  }

  STAGE_A(0, 0);
  STAGE_A(1, 1);
  const int lr = wgrp * 16 + (lane & 15);
  for (int it = 0; it < 160; ++it) {
    __builtin_amdgcn_s_barrier();               // readers of buf[(it+2)%3] (iter it-1) done
    if (it + 2 < 160) STAGE_A(it + 2, (it + 2) % 3);
    if (it == 0) { asm volatile("s_waitcnt vmcnt(8)" ::: "memory"); }
    else         { asm volatile("s_waitcnt vmcnt(16)" ::: "memory"); }  // stage(it) done; stores + 2 stages stay in flight
    __builtin_amdgcn_s_barrier();               // buf[it%3] visible to all waves
    const unsigned short* sA = smem + (it % 3) * 8192;
    f32x4 acc0 = {}, acc1 = {};
#pragma unroll
    for (int kf = 0; kf < 8; ++kf) {
      const int ch = (kf * 4 + (lane >> 4)) ^ (lr & 7);
      const bf16x8 af = __builtin_bit_cast(bf16x8, *(const u16x8*)(sA + lr * 256 + (ch << 3)));
      acc0 = __builtin_amdgcn_mfma_f32_16x16x32_bf16(af, bfr[0][kf], acc0, 0, 0, 0);
      acc1 = __builtin_amdgcn_mfma_f32_16x16x32_bf16(af, bfr[1][kf], acc1, 0, 0, 0);
    }
    const size_t row0 = (size_t)it * 32 + wgrp * 16 + (lane >> 4) * 4;
    float* o0 = out + row0 * V_SZ + n_base + (lane & 15);
#pragma unroll
    for (int i = 0; i < 4; ++i) {
      o0[(size_t)i * V_SZ]      = acc0[i] + bv0;
      o0[(size_t)i * V_SZ + 16] = acc1[i] + bv1;
    }
  }
#undef STAGE_A
}

extern "C" void kernel_launch(void* const* d_in, const int* in_sizes, int n_in,
                              void* d_out, int out_size, void* d_ws, size_t ws_size,
                              hipStream_t stream) {
  (void)in_sizes; (void)n_in; (void)out_size; (void)ws_size;
  const float* inputPrev = (const float*)d_in[0];
  const float* inputNext = (const float*)d_in[1];
  const float* context   = (const float*)d_in[2];
  const float* hidden1   = (const float*)d_in[3];
  const float* hidden2   = (const float*)d_in[4];
  const float* Wih_p = (const float*)d_in[5];
  const float* Whh_p = (const float*)d_in[6];
  const float* bih_p = (const float*)d_in[7];
  const float* bhh_p = (const float*)d_in[8];
  const float* Wih_n = (const float*)d_in[9];
  const float* Whh_n = (const float*)d_in[10];
  const float* bih_n = (const float*)d_in[11];
  const float* bhh_n = (const float*)d_in[12];
  const float* Wp = (const float*)d_in[13];
  const float* bp = (const float*)d_in[14];
  float* out = (float*)d_out;

  // workspace carve (16B-aligned); total ~25.6 MB
  char* ws = (char*)d_ws;
  float* xg_all        = (float*)(ws + 0);            // [2][20][128][1024] f32 = 20,971,520
  float* ctxg          = (float*)(ws + 20971520);     // [2][128][1024] f32    =  1,048,576
  unsigned short* hsb  = (unsigned short*)(ws + 22020096);  // [2][21][128][256] bf16 swz = 2,752,512
  unsigned short* whhb = (unsigned short*)(ws + 24772608);  // [2][8][96][256] bf16 swz   =   786,432

  k_prep<<<1792, 256, 0, stream>>>(Whh_p, Whh_n, hidden1, hidden2, whhb, hsb);
  k_ctx_gemm<<<128, 256, 0, stream>>>(context, Wih_p, Wih_n, bih_p, bhh_p, bih_n, bhh_n, ctxg);
  k_in_gemm<<<1280, 256, 0, stream>>>(inputPrev, inputNext, Wih_p, Wih_n, ctxg, xg_all);
  for (int t = 0; t < T_STEPS; ++t)
    k_step<<<16, 256, 0, stream>>>(hsb, whhb, xg_all, hsb, t);
  k_proj<<<500, 256, 0, stream>>>(hsb, Wp, bp, out);
}

// Round 3
// 372.011 us; speedup vs baseline: 2.3545x; 1.3095x over previous
//
#include <hip/hip_runtime.h>
#include <cstdint>
#include <cstddef>

#define T_STEPS 20
#define B_SZ 128
#define H_SZ 256
#define E_SZ 128
#define C_SZ 512
#define V_SZ 32000
#define G3H 768

typedef __bf16 bf16x8 __attribute__((ext_vector_type(8)));
typedef float f32x4 __attribute__((ext_vector_type(4)));
typedef unsigned short u16x8 __attribute__((ext_vector_type(8)));

#define AS1 __attribute__((address_space(1)))
#define AS3 __attribute__((address_space(3)))

__device__ __forceinline__ unsigned short f2bf(float f) {
  unsigned int u = __builtin_bit_cast(unsigned int, f);
  u += 0x7fffu + ((u >> 16) & 1u);   // round-to-nearest-even
  return (unsigned short)(u >> 16);
}

// ---------- K00: zero the grid-sync counters (re-run every call -> deterministic) ----------
__global__ void k_zero(int* __restrict__ c) {
  if (threadIdx.x < 64) c[threadIdx.x] = 0;
}

// ---------- K0: prep — Whh (i,g,o rows) -> bf16 pre-swizzled panels; h0 -> hsb slot 0 ----------
// whh_bs layout: [l][tt(16)][n(48)][k(256)] bf16; n: 0-15=i,16-31=g,32-47=o for h-cols tt*16+(n&15)
//                element (n,k) holds Whh[row(n)][k ^ ((n&7)<<3)]
// hsb layout:    [l][slot(21)][b(128)][k(256)] bf16, element (b,k) holds h[b][k ^ ((b&7)<<3)]
__global__ __launch_bounds__(256) void k_prep(const float* __restrict__ Whh_p,
    const float* __restrict__ Whh_n, const float* __restrict__ h1, const float* __restrict__ h2,
    unsigned short* __restrict__ whh_bs, unsigned short* __restrict__ hsb) {
  const int idx = blockIdx.x * 256 + threadIdx.x;
  const int NW = 2 * 16 * 48 * 256;
  if (idx < NW) {
    const int k = idx & 255;
    const int n = (idx >> 8) % 48;
    const int tt = ((idx >> 8) / 48) & 15;
    const int l = idx / (16 * 48 * 256);
    const int gate = n >> 4;
    const int c = n & 15;
    const int row = (gate == 0 ? 0 : (gate == 1 ? 512 : 768)) + tt * 16 + c;
    const int ksrc = (k & 7) | (((k >> 3) ^ (n & 7)) << 3);
    const float* W = l ? Whh_n : Whh_p;
    whh_bs[idx] = f2bf(W[(size_t)row * 256 + ksrc]);
  } else {
    const int i2 = idx - NW;          // [2][128][256]
    const int k = i2 & 255;
    const int b = (i2 >> 8) & 127;
    const int l = i2 >> 15;
    const int ksrc = (k & 7) | (((k >> 3) ^ (b & 7)) << 3);
    const float* h = l ? h2 : h1;     // [1,256] broadcast row
    hsb[(size_t)(l * 21) * 32768 + (size_t)b * 256 + k] = f2bf(h[ksrc]);
  }
}

// ---------- K1a: ctxg[l,b,g] = context[b,:] @ Wih_l[row(g),128:640] + bih + bhh (f-gate dropped) ----------
__global__ __launch_bounds__(256) void k_ctx_gemm(const float* __restrict__ context,
    const float* __restrict__ Wih_p, const float* __restrict__ Wih_n,
    const float* __restrict__ bih_p, const float* __restrict__ bhh_p,
    const float* __restrict__ bih_n, const float* __restrict__ bhh_n,
    float* __restrict__ ctxg) {
  const int bid = blockIdx.x;          // 96 blocks: l(2) x btile(16) x gtile(3)
  const int l = bid / 48;
  const int bt = (bid / 3) & 15;
  const int gt = bid % 3;
  const int b0 = bt * 8;
  const int g = gt * 256 + threadIdx.x;        // compact col in [0,768)
  const int row = g + (gt > 0 ? 256 : 0);      // skip dead f-gate rows [256,512)
  __shared__ float csh[8][C_SZ];
  for (int i = threadIdx.x; i < 8 * C_SZ; i += 256)
    csh[i >> 9][i & 511] = context[(size_t)(b0 + (i >> 9)) * C_SZ + (i & 511)];
  __syncthreads();
  const float* W = (l ? Wih_n : Wih_p) + (size_t)row * 640 + E_SZ;
  float acc[8] = {};
  for (int c = 0; c < C_SZ; c += 4) {
    const float4 w = *(const float4*)(W + c);
#pragma unroll
    for (int bb = 0; bb < 8; ++bb) {
      const float4 h = *(const float4*)(&csh[bb][c]);
      acc[bb] += w.x * h.x + w.y * h.y + w.z * h.z + w.w * h.w;
    }
  }
  const float bias = l ? (bih_n[row] + bhh_n[row]) : (bih_p[row] + bhh_p[row]);
#pragma unroll
  for (int bb = 0; bb < 8; ++bb)
    ctxg[((size_t)l * B_SZ + b0 + bb) * G3H + g] = acc[bb] + bias;
}

// ---------- K1b: xg[l,r,g] = input_l[r,:] @ Wih_l[row(g),0:128] + ctxg[l, r&127, g] ----------
__global__ __launch_bounds__(256) void k_in_gemm(const float* __restrict__ inP,
    const float* __restrict__ inN,
    const float* __restrict__ Wih_p, const float* __restrict__ Wih_n,
    const float* __restrict__ ctxg, float* __restrict__ xg) {
  const int bid = blockIdx.x;          // 960 blocks: l(2) x rowtile(160) x gtile(3)
  const int l = bid / 480;
  const int rest = bid % 480;
  const int rt = rest / 3;
  const int gt = rest % 3;
  const int r0 = rt * 16;
  const int g = gt * 256 + threadIdx.x;
  const int row = g + (gt > 0 ? 256 : 0);
  __shared__ float ish[16][E_SZ];
  const float* inp = l ? inN : inP;
  for (int i = threadIdx.x; i < 16 * E_SZ; i += 256)
    ish[i >> 7][i & 127] = inp[(size_t)(r0 + (i >> 7)) * E_SZ + (i & 127)];
  __syncthreads();
  const float* W = (l ? Wih_n : Wih_p) + (size_t)row * 640;
  float acc[16] = {};
  for (int k = 0; k < E_SZ; k += 4) {
    const float4 w = *(const float4*)(W + k);
#pragma unroll
    for (int rr = 0; rr < 16; ++rr) {
      const float4 h = *(const float4*)(&ish[rr][k]);
      acc[rr] += w.x * h.x + w.y * h.y + w.z * h.z + w.w * h.w;
    }
  }
#pragma unroll
  for (int rr = 0; rr < 16; ++rr) {
    const int b = (r0 + rr) & 127;
    const float cv = ctxg[((size_t)l * B_SZ + b) * G3H + g];
    xg[((size_t)l * (T_STEPS * B_SZ) + r0 + rr) * G3H + g] = acc[rr] + cv;
  }
}

// ---------- K2: ALL 20 LSTM steps, persistent kernel with agent-scope grid sync ----------
// grid 32 = l(2) x tt(16); block 256 = 4 waves. Block owns h-cols [tt*16, tt*16+16)
// (N=48 gate rows: i,g,o x 16), M=128 batches, K=256. Whh panel LDS-resident across all steps.
__global__ __launch_bounds__(256, 1) void k_steps(const unsigned short* __restrict__ hsb_in,
    const unsigned short* __restrict__ whh_bs, const float* __restrict__ xg,
    unsigned short* __restrict__ hsb, int* __restrict__ cnt) {
  __shared__ unsigned short wls[48 * 256];    // 24 KB, loaded once
  __shared__ unsigned short hls[128 * 256];   // 64 KB, re-staged per step
  __shared__ float xls[128 * 3 * 16];         // 24 KB xg slice per step
  const int tid = threadIdx.x;
  const int lane = tid & 63;
  const int wave = tid >> 6;
  const int l = blockIdx.x >> 4;
  const int tt = blockIdx.x & 15;

  // Whh panel (once)
  {
    const unsigned short* wsrc = whh_bs + (size_t)(l * 16 + tt) * 12288 + tid * 8;
#pragma unroll
    for (int i = 0; i < 6; ++i)
      __builtin_amdgcn_global_load_lds((const AS1 void*)(wsrc + i * 2048),
                                       (AS3 void*)(wls + tid * 8 + i * 2048), 16, 0, 0);
  }

  for (int t = 0; t < T_STEPS; ++t) {
    // stage h(t) [full 128x256] and xg slice for this block's 16 h-cols
    const unsigned short* hsrc = hsb_in + (size_t)(l * 21 + t) * 32768 + tid * 8;
#pragma unroll
    for (int i = 0; i < 16; ++i)
      __builtin_amdgcn_global_load_lds((const AS1 void*)(hsrc + i * 2048),
                                       (AS3 void*)(hls + tid * 8 + i * 2048), 16, 0, 0);
    const size_t xgbase = ((size_t)(l * T_STEPS + t) * B_SZ) * G3H;
#pragma unroll
    for (int i = 0; i < 6; ++i) {
      const int q = tid + i * 256;            // 16B chunk index, 1536 total
      const int b = q / 12;
      const int r = q - b * 12;
      const int gate = r >> 2;
      const int cg = r & 3;
      const float* src = xg + xgbase + (size_t)b * G3H + gate * 256 + tt * 16 + cg * 4;
      __builtin_amdgcn_global_load_lds((const AS1 void*)src,
                                       (AS3 void*)((char*)xls + q * 16), 16, 0, 0);
    }
    asm volatile("s_waitcnt vmcnt(0)" ::: "memory");
    __builtin_amdgcn_s_barrier();

    // MFMA: D[b][n] = sum_k h[b][k] * Whh[n][k]
    f32x4 acc[2][3] = {};
#pragma unroll
    for (int kf = 0; kf < 8; ++kf) {
      const int ch = kf * 4 + (lane >> 4);
      bf16x8 bf[3];
#pragma unroll
      for (int nt = 0; nt < 3; ++nt) {
        const int n = nt * 16 + (lane & 15);
        bf[nt] = __builtin_bit_cast(bf16x8, *(const u16x8*)(wls + n * 256 + ((ch ^ (n & 7)) << 3)));
      }
#pragma unroll
      for (int m = 0; m < 2; ++m) {
        const int b = wave * 32 + m * 16 + (lane & 15);
        const bf16x8 af = __builtin_bit_cast(bf16x8, *(const u16x8*)(hls + b * 256 + ((ch ^ (b & 7)) << 3)));
#pragma unroll
        for (int nt = 0; nt < 3; ++nt)
          acc[m][nt] = __builtin_amdgcn_mfma_f32_16x16x32_bf16(af, bf[nt], acc[m][nt], 0, 0, 0);
      }
    }

    // epilogue: activations (f-gate dead: c0==0) + swizzled bf16 h-store
    unsigned short* hout = hsb + (size_t)(l * 21 + 1 + t) * 32768;
#pragma unroll
    for (int m = 0; m < 2; ++m) {
#pragma unroll
      for (int i = 0; i < 4; ++i) {
        const int b = wave * 32 + m * 16 + (lane >> 4) * 4 + i;
        const int col = lane & 15;
        const float gi = xls[(b * 3 + 0) * 16 + col] + acc[m][0][i];
        const float gg = xls[(b * 3 + 1) * 16 + col] + acc[m][1][i];
        const float go = xls[(b * 3 + 2) * 16 + col] + acc[m][2][i];
        const float c = (1.0f / (1.0f + expf(-gi))) * tanhf(gg);
        const float h = (1.0f / (1.0f + expf(-go))) * tanhf(c);
        const int j = tt * 16 + col;
        const int kpos = (j & 7) | (((j >> 3) ^ (b & 7)) << 3);
        hout[(size_t)b * 256 + kpos] = f2bf(h);
      }
    }

    if (t < T_STEPS - 1) {
      // release own h-slice, wait for all 16 producers of this lstm
      asm volatile("s_waitcnt vmcnt(0)" ::: "memory");   // every wave drains its stores
      __syncthreads();
      if (tid == 0) {
        __hip_atomic_fetch_add(&cnt[l * T_STEPS + t], 1, __ATOMIC_RELEASE, __HIP_MEMORY_SCOPE_AGENT);
        while (__hip_atomic_load(&cnt[l * T_STEPS + t], __ATOMIC_RELAXED, __HIP_MEMORY_SCOPE_AGENT) < 16)
          __builtin_amdgcn_s_sleep(1);
      }
      __syncthreads();
      __builtin_amdgcn_fence(__ATOMIC_ACQUIRE, "agent"); // invalidate L1/L2 before re-reading h
    }
  }
}

// ---------- K3: projection  out[5120,32000] = hs_bf16[5120,256] @ Wp[32000,256]^T + bp ----------
// 500 blocks x 64-col strip. Wp panel converted f32->bf16 into register B-frags once.
// A tiles (32 rows) triple-buffered via global_load_lds, counted vmcnt, raw barriers.
// Output via nontemporal stores (pure streaming, keep L2 for A/B reads).
__global__ __launch_bounds__(256, 2) void k_proj(const unsigned short* __restrict__ hsb,
    const float* __restrict__ Wp, const float* __restrict__ bias, float* __restrict__ out) {
  __shared__ unsigned short smem[3 * 32 * 256];   // 3 x 16 KB A buffers
  const int tid = threadIdx.x;
  const int lane = tid & 63;
  const int wave = tid >> 6;
  const int wgrp = wave >> 1;       // row half of 32-row tile
  const int wc = wave & 1;          // col half of 64-col strip
  const int n_base = blockIdx.x * 64 + wc * 32;
  // B panel -> registers (bf16 frags)
  bf16x8 bfr[2][8];
#pragma unroll
  for (int nt = 0; nt < 2; ++nt) {
    const int n_g = n_base + nt * 16 + (lane & 15);
    const float* src = Wp + (size_t)n_g * 256 + (lane >> 4) * 8;
#pragma unroll
    for (int kf = 0; kf < 8; ++kf) {
      const float4 a = *(const float4*)(src + kf * 32);
      const float4 b = *(const float4*)(src + kf * 32 + 4);
      u16x8 u;
      u[0] = f2bf(a.x); u[1] = f2bf(a.y); u[2] = f2bf(a.z); u[3] = f2bf(a.w);
      u[4] = f2bf(b.x); u[5] = f2bf(b.y); u[6] = f2bf(b.z); u[7] = f2bf(b.w);
      bfr[nt][kf] = __builtin_bit_cast(bf16x8, u);
    }
  }
  const float bv0 = bias[n_base + (lane & 15)];
  const float bv1 = bias[n_base + 16 + (lane & 15)];

#define STAGE_A(IT, BUF)                                                                   \
  {                                                                                        \
    const int it_ = (IT);                                                                  \
    const int l_ = it_ >= 80;                                                              \
    const int t_ = (it_ - l_ * 80) >> 2;                                                   \
    const int b0_ = (it_ & 3) * 32;                                                        \
    const unsigned short* src_ = hsb + (size_t)(l_ * 21 + 1 + t_) * 32768 + b0_ * 256 + tid * 8; \
    unsigned short* dst_ = smem + (BUF) * 8192 + tid * 8;                                  \
    _Pragma("unroll")                                                                      \
    for (int i_ = 0; i_ < 4; ++i_)                                                         \
      __builtin_amdgcn_global_load_lds((const AS1 void*)(src_ + i_ * 2048),                \
                                       (AS3 void*)(dst_ + i_ * 2048), 16, 0, 0);           \
  }

  STAGE_A(0, 0);
  STAGE_A(1, 1);
  const int lr = wgrp * 16 + (lane & 15);
  for (int it = 0; it < 160; ++it) {
    __builtin_amdgcn_s_barrier();               // readers of buf[(it+2)%3] (iter it-1) done
    if (it + 2 < 160) STAGE_A(it + 2, (it + 2) % 3);
    if (it == 0) { asm volatile("s_waitcnt vmcnt(8)" ::: "memory"); }
    else         { asm volatile("s_waitcnt vmcnt(16)" ::: "memory"); }  // stage(it) done; stores + 2 stages in flight
    __builtin_amdgcn_s_barrier();               // buf[it%3] visible to all waves
    const unsigned short* sA = smem + (it % 3) * 8192;
    f32x4 acc0 = {}, acc1 = {};
#pragma unroll
    for (int kf = 0; kf < 8; ++kf) {
      const int ch = (kf * 4 + (lane >> 4)) ^ (lr & 7);
      const bf16x8 af = __builtin_bit_cast(bf16x8, *(const u16x8*)(sA + lr * 256 + (ch << 3)));
      acc0 = __builtin_amdgcn_mfma_f32_16x16x32_bf16(af, bfr[0][kf], acc0, 0, 0, 0);
      acc1 = __builtin_amdgcn_mfma_f32_16x16x32_bf16(af, bfr[1][kf], acc1, 0, 0, 0);
    }
    const size_t row0 = (size_t)it * 32 + wgrp * 16 + (lane >> 4) * 4;
    float* o0 = out + row0 * V_SZ + n_base + (lane & 15);
#pragma unroll
    for (int i = 0; i < 4; ++i) {
      __builtin_nontemporal_store(acc0[i] + bv0, &o0[(size_t)i * V_SZ]);
      __builtin_nontemporal_store(acc1[i] + bv1, &o0[(size_t)i * V_SZ + 16]);
    }
  }
#undef STAGE_A
}

extern "C" void kernel_launch(void* const* d_in, const int* in_sizes, int n_in,
                              void* d_out, int out_size, void* d_ws, size_t ws_size,
                              hipStream_t stream) {
  (void)in_sizes; (void)n_in; (void)out_size; (void)ws_size;
  const float* inputPrev = (const float*)d_in[0];
  const float* inputNext = (const float*)d_in[1];
  const float* context   = (const float*)d_in[2];
  const float* hidden1   = (const float*)d_in[3];
  const float* hidden2   = (const float*)d_in[4];
  const float* Wih_p = (const float*)d_in[5];
  const float* Whh_p = (const float*)d_in[6];
  const float* bih_p = (const float*)d_in[7];
  const float* bhh_p = (const float*)d_in[8];
  const float* Wih_n = (const float*)d_in[9];
  const float* Whh_n = (const float*)d_in[10];
  const float* bih_n = (const float*)d_in[11];
  const float* bhh_n = (const float*)d_in[12];
  const float* Wp = (const float*)d_in[13];
  const float* bp = (const float*)d_in[14];
  float* out = (float*)d_out;

  // workspace carve (16B-aligned); total ~20.1 MB
  char* ws = (char*)d_ws;
  float* xg_all        = (float*)(ws + 0);                   // [2][20][128][768] f32 = 15,728,640
  float* ctxg          = (float*)(ws + 15728640);            // [2][128][768] f32    =    786,432
  unsigned short* hsb  = (unsigned short*)(ws + 16515072);   // [2][21][128][256] bf16 swz = 2,752,512
  unsigned short* whhb = (unsigned short*)(ws + 19267584);   // [2][16][48][256] bf16 swz  =   786,432
  int* cnt             = (int*)(ws + 20054016);              // 40 grid-sync counters

  k_zero<<<1, 64, 0, stream>>>(cnt);
  k_prep<<<1792, 256, 0, stream>>>(Whh_p, Whh_n, hidden1, hidden2, whhb, hsb);
  k_ctx_gemm<<<96, 256, 0, stream>>>(context, Wih_p, Wih_n, bih_p, bhh_p, bih_n, bhh_n, ctxg);
  k_in_gemm<<<960, 256, 0, stream>>>(inputPrev, inputNext, Wih_p, Wih_n, ctxg, xg_all);
  k_steps<<<32, 256, 0, stream>>>(hsb, whhb, xg_all, hsb, cnt);
  k_proj<<<500, 256, 0, stream>>>(hsb, Wp, bp, out);
}